// Round 4
// baseline (1223.859 us; speedup 1.0000x reference)
//
#include <hip/hip_runtime.h>

// DynamicRouting: grouped 1x1 conv (G=8, FI=FO=64) + 3-iter sigmoid routing.
// v4: de-risked deep pipeline (counted vmcnt, T3+T4), 512-thread WGs.
//   Changes vs failed v3/v3b (container-level death, no counters):
//   - LDS ring 4 -> 3 buffers: 48 KiB (64 KiB static was at the HW limit).
//   - __builtin_amdgcn_s_barrier() (m201-verified) instead of asm s_barrier.
//   - plain __launch_bounds__(512), no min-waves hint.
// Structure:
//  - WG = 512 threads = 8 waves, one per fo-eighth. Thread = (pixel p, wave q).
//    con[8][8] per thread.
//  - chunk = one group = 64 ch x 64 px = 16 KB, staged via global_load_lds
//    width=16 (2 per thread per chunk). Ring of 3 (48 KB), prefetch depth 2.
//  - per chunk c: s_waitcnt vmcnt(2) (chunk-c stage loads are the oldest FIFO
//    entries -> retired; chunk c+1 stays IN FLIGHT across the barrier)
//    -> s_barrier -> issue stage(c+2) -> compute(c).
//    stage(c+2) overwrites buf[(c-1)%3]; its last reader compute(c-1) is
//    ordered by the barrier just passed. vmcnt counting is robust to
//    compiler-issued weight loads (younger FIFO entries; oldest retire first).
//  - packed fp32 (fma on float2) jp-outer / f-inner, acc[8] v2f.
//  - routing scratch unioned into the staging ring: pbuf = buf0 (last read
//    compute(6), ordered by barrier c=7); alphaS/betaS = buf1 head (last read
//    compute(7), first write after routing's first __syncthreads()).

#define NG 8
#define NFO 64
#define NFI 64
#define NB 32
#define NH 64
#define NW 64
#define HW (NH * NW)

typedef float v2f __attribute__((ext_vector_type(2)));

__device__ __forceinline__ void stage_piece(const float* gsrc, float* ldst) {
    // per-lane global src; wave-uniform LDS dst: lane L writes 16B at ldst+L*16
    __builtin_amdgcn_global_load_lds(
        (const __attribute__((address_space(1))) void*)gsrc,
        (__attribute__((address_space(3))) void*)ldst, 16, 0, 0);
}

__global__ __launch_bounds__(512) void dynrout_kernel(
    const float* __restrict__ x, const float* __restrict__ weight,
    const float* __restrict__ bias, float* __restrict__ out)
{
    const int tid = threadIdx.x;
    const int p = tid & 63;
    const int q = __builtin_amdgcn_readfirstlane(tid >> 6);  // wave id = fo-eighth

    const int wg = blockIdx.x;
    const int b = wg >> 6;
    const int h = wg & 63;

    __shared__ __align__(16) float smem[12288];  // 48 KiB: 3 x 16KB chunk ring

    const float* xrow = x + (size_t)b * (NG * NFI) * HW + (size_t)h * NW;
    // lane-private source: wave q stages channels q*8..q*8+7 of each chunk,
    // lane L covers (ch = +(L>>4), px = (L&15)*4 .. +3) within a 4-ch piece.
    const float* gsrc0 = xrow + ((size_t)(q * 8 + (p >> 4))) * HW + (size_t)(p & 15) * 4;
    const int ldst0 = q * 8 * 64;  // wave-uniform float index into chunk buffer

    float con[8][8];

    // ---- prologue: stage chunks 0,1 (4 loads in flight) ----
#pragma unroll
    for (int g = 0; g < 2; ++g) {
        const float* s0 = gsrc0 + (size_t)(g * 64) * HW;
        float* dst = smem + g * 4096 + ldst0;
        stage_piece(s0, dst);
        stage_piece(s0 + 4 * HW, dst + 256);
    }

    // ---- main loop: chunk c = group c ----
#pragma unroll
    for (int c = 0; c < 8; ++c) {
        // chunk-c stage loads (oldest FIFO entries) retired; chunk c+1 stays
        // in flight across the barrier
        if (c < 7) asm volatile("s_waitcnt vmcnt(2)" ::: "memory");
        else       asm volatile("s_waitcnt vmcnt(0)" ::: "memory");
        __builtin_amdgcn_s_barrier();  // all waves' chunk-c data landed

        if (c < 6) {  // prefetch chunk c+2 into buf[(c+2)%3] (= buf[(c-1)%3])
            const float* s0 = gsrc0 + (size_t)((c + 2) * 64) * HW;
            float* dst = smem + ((c + 2) % 3) * 4096 + ldst0;
            stage_piece(s0, dst);
            stage_piece(s0 + 4 * HW, dst + 256);
        }

        const float* buf = smem + (c % 3) * 4096;            // [64 ch][64 px]
        const float* wrow = weight + ((size_t)(c * 64 + q * 8)) * 64;

        v2f acc[8];
#pragma unroll
        for (int f = 0; f < 8; ++f) acc[f] = (v2f){0.f, 0.f};
#pragma unroll
        for (int jp = 0; jp < 32; ++jp) {
            v2f xv;
            xv.x = buf[(2 * jp) * 64 + p];
            xv.y = buf[(2 * jp + 1) * 64 + p];
#pragma unroll
            for (int f = 0; f < 8; ++f) {
                const v2f wv = *(const v2f*)(wrow + f * 64 + 2 * jp);
                acc[f] = __builtin_elementwise_fma(wv, xv, acc[f]);
            }
        }
#pragma unroll
        for (int f = 0; f < 8; ++f) con[c][f] = acc[f].x + acc[f].y;
    }

    // ---- routing (scratch unioned into staging ring) ----
    float* pbuf   = smem;          // [8 waves][8 g][64 px] = buf0
    float* alphaS = smem + 4096;   // buf1 head
    float* betaS  = smem + 4608;

    float v[8];

    // iter 0: alpha = sigmoid(0) = 0.5
#pragma unroll
    for (int f = 0; f < 8; ++f) {
        float s = con[0][f];
#pragma unroll
        for (int g = 1; g < 8; ++g) s += con[g][f];
        v[f] = 0.5f * s;
    }
#pragma unroll
    for (int g = 0; g < 8; ++g) {
        float s = 0.f;
#pragma unroll
        for (int f = 0; f < 8; ++f) s = fmaf(v[f], con[g][f], s);
        pbuf[(q * 8 + g) * 64 + p] = s;
    }
    __syncthreads();
    {
        const int gg = tid >> 6, pp = tid & 63;
        float bs = 0.f;
#pragma unroll
        for (int w = 0; w < 8; ++w) bs += pbuf[(w * 8 + gg) * 64 + pp];
        betaS[gg * 64 + pp] = bs;
        alphaS[gg * 64 + pp] = 1.f / (1.f + __expf(-bs));
    }
    __syncthreads();

    // iter 1
    float a[8];
#pragma unroll
    for (int g = 0; g < 8; ++g) a[g] = alphaS[g * 64 + p];
#pragma unroll
    for (int f = 0; f < 8; ++f) {
        float s = 0.f;
#pragma unroll
        for (int g = 0; g < 8; ++g) s = fmaf(a[g], con[g][f], s);
        v[f] = s;
    }
#pragma unroll
    for (int g = 0; g < 8; ++g) {
        float s = 0.f;
#pragma unroll
        for (int f = 0; f < 8; ++f) s = fmaf(v[f], con[g][f], s);
        pbuf[(q * 8 + g) * 64 + p] = s;
    }
    __syncthreads();
    {
        const int gg = tid >> 6, pp = tid & 63;
        float bs = betaS[gg * 64 + pp];
#pragma unroll
        for (int w = 0; w < 8; ++w) bs += pbuf[(w * 8 + gg) * 64 + pp];
        alphaS[gg * 64 + pp] = 1.f / (1.f + __expf(-bs));
    }
    __syncthreads();

    // iter 2: out = sum_g alpha2*con + bias
#pragma unroll
    for (int g = 0; g < 8; ++g) a[g] = alphaS[g * 64 + p];

    const float* bq = bias + q * 8;
    float* orow = out + (((size_t)b * NFO + (size_t)q * 8) * NH + h) * NW + p;
#pragma unroll
    for (int f = 0; f < 8; ++f) {
        float s = bq[f];
#pragma unroll
        for (int g = 0; g < 8; ++g) s = fmaf(a[g], con[g][f], s);
        orow[(size_t)f * HW] = s;
    }
}

extern "C" void kernel_launch(void* const* d_in, const int* in_sizes, int n_in,
                              void* d_out, int out_size, void* d_ws, size_t ws_size,
                              hipStream_t stream) {
    const float* x      = (const float*)d_in[0];
    const float* weight = (const float*)d_in[1];
    const float* bias   = (const float*)d_in[2];
    float* out = (float*)d_out;

    dynrout_kernel<<<dim3(NB * NH), dim3(512), 0, stream>>>(x, weight, bias, out);
}

// Round 5
// 564.078 us; speedup vs baseline: 2.1697x; 2.1697x over previous
//
#include <hip/hip_runtime.h>

// DynamicRouting: grouped 1x1 conv (G=8, FI=FO=64) + 3-iter sigmoid routing.
// v5 = v2's PROVEN codegen (256 thr, VGPR 84, weights->scalar loads, zero
// scratch, 305 us) with ONLY the sync structure changed to a counted-vmcnt
// ring (T3+T4). v4 post-mortem: 512-thr con[8][8] spilled ~1 GB of scratch
// (WRITE 774 MB vs 32 MB output) under the 128-VGPR default cap -> never
// again; conv loop below is byte-identical to v2.
//
//  - WG = 256 threads, one per (pixel p = tid&63, fo-quarter q = tid>>6);
//    con[8][16] per thread (AGPR-backed at VGPR_Count 84 in v2).
//  - chunk = 32 ch x 64 px = 8 KB, 16 chunks; staged via global_load_lds
//    width=16 (2 per thread per chunk). Ring of 3 (24 KB), prefetch depth 2.
//  - per chunk c: s_waitcnt vmcnt(2)  [chunk-c stage loads retired; chunk
//    c+1's 2 loads stay IN FLIGHT across the barrier -- weights are scalar
//    loads (lgkmcnt), so the vmcnt FIFO holds only stage loads]
//    -> s_barrier -> issue stage(c+2) -> compute(c).
//    stage(c+2) overwrites buf[(c-1)%3]; its readers (compute(c-1)) are
//    ordered by the barrier just passed.
//  - __syncthreads() after the loop: routing scratch unions into buf0
//    (chunk 15's buffer) + buf1 head.

#define NG 8
#define NFO 64
#define NFI 64
#define NB 32
#define NH 64
#define NW 64
#define HW (NH * NW)

typedef float v2f __attribute__((ext_vector_type(2)));

__device__ __forceinline__ void stage_piece(const float* gsrc, float* ldst) {
    // per-lane global src; wave-uniform LDS dst: lane L writes 16B at ldst+L*16
    __builtin_amdgcn_global_load_lds(
        (const __attribute__((address_space(1))) void*)gsrc,
        (__attribute__((address_space(3))) void*)ldst, 16, 0, 0);
}

__global__ __launch_bounds__(256) void dynrout_kernel(
    const float* __restrict__ x, const float* __restrict__ weight,
    const float* __restrict__ bias, float* __restrict__ out)
{
    const int tid = threadIdx.x;
    const int p = tid & 63;
    const int q = __builtin_amdgcn_readfirstlane(tid >> 6);  // fo-quarter, wave-uniform

    const int wg = blockIdx.x;
    const int b = wg >> 6;
    const int h = wg & 63;

    __shared__ __align__(16) float smem[6144];  // 24 KiB: 3 x 8KB chunk ring

    const float* xrow = x + (size_t)b * (NG * NFI) * HW + (size_t)h * NW;
    // per-lane source inside a 4-channel (1KB) piece: lane L -> ch +(L>>4), px (L&15)*4
    const float* gpiece = xrow + (size_t)(p >> 4) * HW + (size_t)(p & 15) * 4;

    float con[8][16];
#pragma unroll
    for (int g = 0; g < 8; ++g)
#pragma unroll
        for (int f = 0; f < 16; ++f) con[g][f] = 0.f;

    // ---- prologue: stage chunks 0,1 (4 loads in flight) ----
#pragma unroll
    for (int cc = 0; cc < 2; ++cc) {
        float* dst = smem + cc * 2048;
        const float* g0 = gpiece + (size_t)(cc * 32) * HW;
        stage_piece(g0 + (size_t)(q * 8) * HW,     dst + (q * 2) * 256);
        stage_piece(g0 + (size_t)(q * 8 + 4) * HW, dst + (q * 2 + 1) * 256);
    }

    // ---- main loop: chunk c = channels [c*32, c*32+32), group g = c>>1 ----
#pragma unroll
    for (int c = 0; c < 16; ++c) {
        // chunk-c stage loads (oldest vmcnt entries) retired; chunk c+1 stays
        // in flight across the barrier
        if (c < 15) asm volatile("s_waitcnt vmcnt(2)" ::: "memory");
        else        asm volatile("s_waitcnt vmcnt(0)" ::: "memory");
        __builtin_amdgcn_s_barrier();  // all waves' chunk-c data landed

        if (c < 14) {  // prefetch chunk c+2 into buf[(c+2)%3] (= buf[(c-1)%3])
            float* dst = smem + ((c + 2) % 3) * 2048;
            const float* g0 = gpiece + (size_t)((c + 2) * 32) * HW;
            stage_piece(g0 + (size_t)(q * 8) * HW,     dst + (q * 2) * 256);
            stage_piece(g0 + (size_t)(q * 8 + 4) * HW, dst + (q * 2 + 1) * 256);
        }

        const int g = c >> 1;
        const float* bufp = smem + (c % 3) * 2048;  // [32 ch][64 px]

        v2f xp[16];
#pragma unroll
        for (int jp = 0; jp < 16; ++jp) {
            xp[jp].x = bufp[(2 * jp) * 64 + p];
            xp[jp].y = bufp[(2 * jp + 1) * 64 + p];
        }

        const float* wq = weight + ((size_t)g * NFO + (size_t)q * 16) * NFI + (c & 1) * 32;
#pragma unroll
        for (int f = 0; f < 16; ++f) {
            const float* wr = wq + (size_t)f * NFI;
            v2f a0 = {0.f, 0.f}, a1 = {0.f, 0.f};
#pragma unroll
            for (int jp = 0; jp < 16; jp += 2) {
                const v2f w0 = *(const v2f*)(wr + 2 * jp);
                const v2f w1 = *(const v2f*)(wr + 2 * jp + 2);
                a0 = __builtin_elementwise_fma(w0, xp[jp], a0);
                a1 = __builtin_elementwise_fma(w1, xp[jp + 1], a1);
            }
            con[g][f] += (a0.x + a1.x) + (a0.y + a1.y);
        }
    }
    __syncthreads();  // compute(15) (reads buf0) done in ALL waves before union reuse

    // ---- routing (scratch unioned into staging ring) ----
    float* pbuf   = smem;          // [4][8][64] partial beta sums = buf0
    float* alphaS = smem + 2048;   // buf1 head
    float* betaS  = smem + 2560;

    float v[16];

    // iter 0: alpha = sigmoid(0) = 0.5; v0 = 0.5 * sum_g con
#pragma unroll
    for (int f = 0; f < 16; ++f) {
        float s = con[0][f];
#pragma unroll
        for (int g = 1; g < 8; ++g) s += con[g][f];
        v[f] = 0.5f * s;
    }
#pragma unroll
    for (int g = 0; g < 8; ++g) {
        float s = 0.f;
#pragma unroll
        for (int f = 0; f < 16; ++f) s = fmaf(v[f], con[g][f], s);
        pbuf[(q * 8 + g) * 64 + p] = s;
    }
    __syncthreads();
    for (int k = tid; k < 512; k += 256) {
        const int gg = k >> 6, pp = k & 63;
        const float bs = pbuf[gg * 64 + pp] + pbuf[512 + gg * 64 + pp] +
                         pbuf[1024 + gg * 64 + pp] + pbuf[1536 + gg * 64 + pp];
        betaS[gg * 64 + pp] = bs;
        alphaS[gg * 64 + pp] = 1.f / (1.f + __expf(-bs));
    }
    __syncthreads();

    // iter 1: v1 = sum_g alpha1*con; beta2 partials
    float a[8];
#pragma unroll
    for (int g = 0; g < 8; ++g) a[g] = alphaS[g * 64 + p];
#pragma unroll
    for (int f = 0; f < 16; ++f) {
        float s = 0.f;
#pragma unroll
        for (int g = 0; g < 8; ++g) s = fmaf(a[g], con[g][f], s);
        v[f] = s;
    }
#pragma unroll
    for (int g = 0; g < 8; ++g) {
        float s = 0.f;
#pragma unroll
        for (int f = 0; f < 16; ++f) s = fmaf(v[f], con[g][f], s);
        pbuf[(q * 8 + g) * 64 + p] = s;
    }
    __syncthreads();
    for (int k = tid; k < 512; k += 256) {
        const int gg = k >> 6, pp = k & 63;
        const float bs = betaS[gg * 64 + pp] +
                         pbuf[gg * 64 + pp] + pbuf[512 + gg * 64 + pp] +
                         pbuf[1024 + gg * 64 + pp] + pbuf[1536 + gg * 64 + pp];
        alphaS[gg * 64 + pp] = 1.f / (1.f + __expf(-bs));
    }
    __syncthreads();

    // iter 2: out = sum_g alpha2*con + bias
#pragma unroll
    for (int g = 0; g < 8; ++g) a[g] = alphaS[g * 64 + p];

    const float* bq = bias + q * 16;
    float* orow = out + (((size_t)b * NFO + (size_t)q * 16) * NH + h) * NW + p;
#pragma unroll
    for (int f = 0; f < 16; ++f) {
        float s = bq[f];
#pragma unroll
        for (int g = 0; g < 8; ++g) s = fmaf(a[g], con[g][f], s);
        orow[(size_t)f * HW] = s;
    }
}

extern "C" void kernel_launch(void* const* d_in, const int* in_sizes, int n_in,
                              void* d_out, int out_size, void* d_ws, size_t ws_size,
                              hipStream_t stream) {
    const float* x      = (const float*)d_in[0];
    const float* weight = (const float*)d_in[1];
    const float* bias   = (const float*)d_in[2];
    float* out = (float*)d_out;

    dynrout_kernel<<<dim3(NB * NH), dim3(256), 0, stream>>>(x, weight, bias, out);
}

// Round 6
// 491.261 us; speedup vs baseline: 2.4913x; 1.1482x over previous
//
#include <hip/hip_runtime.h>

// DynamicRouting: grouped 1x1 conv (G=8, FI=FO=64) + 3-iter sigmoid routing.
// v6: TWO-DISPATCH SPLIT. Post-mortem of v5: counted-vmcnt made ZERO difference
// vs v2 (305 us, VALU 24.7%, identical counters) -> staging/sync theory dead.
// Real bottleneck: con[8][16] = 128 persistent f32/thread => ~200+ total regs
// (unified VGPR+AGPR file; VGPR_Count 84 is only half the story) => 2 waves/SIMD
// (Occupancy 32% = 10/32 waves/CU) => every f-loop latency half-exposed.
// The fused form REQUIRES 128 accumulators; so unfuse:
//   K1 conv:    WG per (b,g,px-tile), acc[16] only, launch_bounds(256,8)
//               -> 8 waves/SIMD, latency hidden by TLP. con -> d_ws (268 MB).
//   K2 routing: streaming read of con + v5 routing block verbatim.
// ws_size guard: if d_ws < 268 MB, launch the proven v5 fused kernel instead
// (host-side constant branch; graph-capture safe).

#define NG 8
#define NFO 64
#define NFI 64
#define NB 32
#define NH 64
#define NW 64
#define HW (NH * NW)   // 4096 pixels per (b, channel) plane

typedef float v2f __attribute__((ext_vector_type(2)));

__device__ __forceinline__ void stage_piece(const float* gsrc, float* ldst) {
    // per-lane global src; wave-uniform LDS dst: lane L writes 16B at ldst+L*16
    __builtin_amdgcn_global_load_lds(
        (const __attribute__((address_space(1))) void*)gsrc,
        (__attribute__((address_space(3))) void*)ldst, 16, 0, 0);
}

// ---------------------------------------------------------------------------
// K1: grouped 1x1 conv.  con[b][g][fo][px] = sum_i w[g][fo][i] * x[b][g*64+i][px]
// Grid = 32 b x 8 g x 64 px-tiles = 16384 WGs, 256 threads.
// Thread = (px p in tile, fo-quarter q). acc[16] in v2f pairs (~32 regs live).
// launch_bounds(256,8): force <=64 VGPRs => 8 waves/SIMD. If this spills,
// WRITE_SIZE blows past 268 MB (falsifier).
// ---------------------------------------------------------------------------
__global__ __launch_bounds__(256, 8) void conv_kernel(
    const float* __restrict__ x, const float* __restrict__ weight,
    float* __restrict__ con)
{
    const int tid = threadIdx.x;
    const int p = tid & 63;
    const int q = __builtin_amdgcn_readfirstlane(tid >> 6);  // fo-quarter

    const int id = blockIdx.x;
    const int t = id & 63;          // px tile (64 px)
    const int g = (id >> 6) & 7;    // group
    const int b = id >> 9;          // batch

    __shared__ __align__(16) float smem[4096];  // [64 ch][64 px] = 16 KB

    // x slab for (b, group g): [64 ch][4096 px], our tile at column t*64
    const float* xg = x + ((size_t)b * (NG * NFI) + (size_t)g * NFI) * HW + t * 64;

    // stage 16 KB: wave q stages channels q*16..q*16+15 as 4 pieces of 4 ch;
    // lane L in a piece covers (ch +(L>>4), px (L&15)*4..+3) — v5-proven pattern.
#pragma unroll
    for (int cc = 0; cc < 4; ++cc) {
        const int chb = q * 16 + cc * 4;
        stage_piece(xg + (size_t)(chb + (p >> 4)) * HW + (p & 15) * 4,
                    smem + chb * 64);
    }
    asm volatile("s_waitcnt vmcnt(0)" ::: "memory");
    __builtin_amdgcn_s_barrier();

    v2f acc[16];
#pragma unroll
    for (int f = 0; f < 16; ++f) acc[f] = (v2f){0.f, 0.f};

    const float* wq = weight + ((size_t)g * NFO + (size_t)q * 16) * NFI;
#pragma unroll
    for (int ib = 0; ib < 8; ++ib) {       // 8 channels per block
        v2f xq[4];
#pragma unroll
        for (int j = 0; j < 4; ++j) {
            xq[j].x = smem[(ib * 8 + 2 * j) * 64 + p];      // stride-1 lanes: no conflict
            xq[j].y = smem[(ib * 8 + 2 * j + 1) * 64 + p];
        }
#pragma unroll
        for (int f = 0; f < 16; ++f) {
            const float* wr = wq + (size_t)f * NFI + ib * 8;   // wave-uniform -> s_load
#pragma unroll
            for (int j = 0; j < 4; ++j) {
                const v2f wv = *(const v2f*)(wr + 2 * j);
                acc[f] = __builtin_elementwise_fma(wv, xq[j], acc[f]);
            }
        }
    }

    // con[b][g][fo][px]: coalesced dword stores
    float* crow = con + (((size_t)(b * NG + g) * NFO + (size_t)q * 16)) * HW
                      + t * 64 + p;
#pragma unroll
    for (int f = 0; f < 16; ++f)
        crow[(size_t)f * HW] = acc[f].x + acc[f].y;
}

// ---------------------------------------------------------------------------
// K2: routing. Grid = 32 b x 64 px-tiles = 2048 WGs, 256 threads.
// Thread = (px p, fo-quarter q): streams con[8][16] (coalesced, stride HW),
// then the v5 routing block verbatim. BW-bound (96 MB); low occupancy is fine.
// ---------------------------------------------------------------------------
__global__ __launch_bounds__(256) void route_kernel(
    const float* __restrict__ con, const float* __restrict__ bias,
    float* __restrict__ out)
{
    const int tid = threadIdx.x;
    const int p = tid & 63;
    const int q = __builtin_amdgcn_readfirstlane(tid >> 6);

    const int id = blockIdx.x;
    const int t = id & 63;          // px tile = h
    const int b = id >> 6;

    __shared__ float pbuf[4][8][64];
    __shared__ float alphaS[8][64];
    __shared__ float betaS[8][64];

    float c[8][16];
#pragma unroll
    for (int g = 0; g < 8; ++g) {
        const float* cr = con + (((size_t)(b * NG + g) * NFO + (size_t)q * 16)) * HW
                              + t * 64 + p;
#pragma unroll
        for (int f = 0; f < 16; ++f) c[g][f] = cr[(size_t)f * HW];
    }

    float v[16];

    // iter 0: alpha = sigmoid(0) = 0.5; v0 = 0.5 * sum_g con
#pragma unroll
    for (int f = 0; f < 16; ++f) {
        float s = c[0][f];
#pragma unroll
        for (int g = 1; g < 8; ++g) s += c[g][f];
        v[f] = 0.5f * s;
    }
#pragma unroll
    for (int g = 0; g < 8; ++g) {
        float s = 0.f;
#pragma unroll
        for (int f = 0; f < 16; ++f) s = fmaf(v[f], c[g][f], s);
        pbuf[q][g][p] = s;
    }
    __syncthreads();
    for (int k = tid; k < 512; k += 256) {
        const int gg = k >> 6, pp = k & 63;
        const float bs = pbuf[0][gg][pp] + pbuf[1][gg][pp] +
                         pbuf[2][gg][pp] + pbuf[3][gg][pp];
        betaS[gg][pp] = bs;
        alphaS[gg][pp] = 1.f / (1.f + __expf(-bs));
    }
    __syncthreads();

    // iter 1
    float a[8];
#pragma unroll
    for (int g = 0; g < 8; ++g) a[g] = alphaS[g][p];
#pragma unroll
    for (int f = 0; f < 16; ++f) {
        float s = 0.f;
#pragma unroll
        for (int g = 0; g < 8; ++g) s = fmaf(a[g], c[g][f], s);
        v[f] = s;
    }
#pragma unroll
    for (int g = 0; g < 8; ++g) {
        float s = 0.f;
#pragma unroll
        for (int f = 0; f < 16; ++f) s = fmaf(v[f], c[g][f], s);
        pbuf[q][g][p] = s;
    }
    __syncthreads();
    for (int k = tid; k < 512; k += 256) {
        const int gg = k >> 6, pp = k & 63;
        const float bs = betaS[gg][pp] +
                         pbuf[0][gg][pp] + pbuf[1][gg][pp] +
                         pbuf[2][gg][pp] + pbuf[3][gg][pp];
        alphaS[gg][pp] = 1.f / (1.f + __expf(-bs));
    }
    __syncthreads();

    // iter 2: out = sum_g alpha2*con + bias
#pragma unroll
    for (int g = 0; g < 8; ++g) a[g] = alphaS[g][p];

    const float* bq = bias + q * 16;
    float* orow = out + (((size_t)b * NFO + (size_t)q * 16) * NH + t) * NW + p;
#pragma unroll
    for (int f = 0; f < 16; ++f) {
        float s = bq[f];
#pragma unroll
        for (int g = 0; g < 8; ++g) s = fmaf(a[g], c[g][f], s);
        orow[(size_t)f * HW] = s;
    }
}

// ---------------------------------------------------------------------------
// Fallback: v5 fused kernel verbatim (known-good 305 us) for small ws.
// ---------------------------------------------------------------------------
__global__ __launch_bounds__(256) void dynrout_kernel(
    const float* __restrict__ x, const float* __restrict__ weight,
    const float* __restrict__ bias, float* __restrict__ out)
{
    const int tid = threadIdx.x;
    const int p = tid & 63;
    const int q = __builtin_amdgcn_readfirstlane(tid >> 6);

    const int wg = blockIdx.x;
    const int b = wg >> 6;
    const int h = wg & 63;

    __shared__ __align__(16) float smem[6144];  // 24 KiB: 3 x 8KB chunk ring

    const float* xrow = x + (size_t)b * (NG * NFI) * HW + (size_t)h * NW;
    const float* gpiece = xrow + (size_t)(p >> 4) * HW + (size_t)(p & 15) * 4;

    float con[8][16];
#pragma unroll
    for (int g = 0; g < 8; ++g)
#pragma unroll
        for (int f = 0; f < 16; ++f) con[g][f] = 0.f;

#pragma unroll
    for (int cc = 0; cc < 2; ++cc) {
        float* dst = smem + cc * 2048;
        const float* g0 = gpiece + (size_t)(cc * 32) * HW;
        stage_piece(g0 + (size_t)(q * 8) * HW,     dst + (q * 2) * 256);
        stage_piece(g0 + (size_t)(q * 8 + 4) * HW, dst + (q * 2 + 1) * 256);
    }

#pragma unroll
    for (int c = 0; c < 16; ++c) {
        if (c < 15) asm volatile("s_waitcnt vmcnt(2)" ::: "memory");
        else        asm volatile("s_waitcnt vmcnt(0)" ::: "memory");
        __builtin_amdgcn_s_barrier();

        if (c < 14) {
            float* dst = smem + ((c + 2) % 3) * 2048;
            const float* g0 = gpiece + (size_t)((c + 2) * 32) * HW;
            stage_piece(g0 + (size_t)(q * 8) * HW,     dst + (q * 2) * 256);
            stage_piece(g0 + (size_t)(q * 8 + 4) * HW, dst + (q * 2 + 1) * 256);
        }

        const int g = c >> 1;
        const float* bufp = smem + (c % 3) * 2048;

        v2f xp[16];
#pragma unroll
        for (int jp = 0; jp < 16; ++jp) {
            xp[jp].x = bufp[(2 * jp) * 64 + p];
            xp[jp].y = bufp[(2 * jp + 1) * 64 + p];
        }

        const float* wq = weight + ((size_t)g * NFO + (size_t)q * 16) * NFI + (c & 1) * 32;
#pragma unroll
        for (int f = 0; f < 16; ++f) {
            const float* wr = wq + (size_t)f * NFI;
            v2f a0 = {0.f, 0.f}, a1 = {0.f, 0.f};
#pragma unroll
            for (int jp = 0; jp < 16; jp += 2) {
                const v2f w0 = *(const v2f*)(wr + 2 * jp);
                const v2f w1 = *(const v2f*)(wr + 2 * jp + 2);
                a0 = __builtin_elementwise_fma(w0, xp[jp], a0);
                a1 = __builtin_elementwise_fma(w1, xp[jp + 1], a1);
            }
            con[g][f] += (a0.x + a1.x) + (a0.y + a1.y);
        }
    }
    __syncthreads();

    float* pbuf   = smem;
    float* alphaS = smem + 2048;
    float* betaS  = smem + 2560;

    float v[16];
#pragma unroll
    for (int f = 0; f < 16; ++f) {
        float s = con[0][f];
#pragma unroll
        for (int g = 1; g < 8; ++g) s += con[g][f];
        v[f] = 0.5f * s;
    }
#pragma unroll
    for (int g = 0; g < 8; ++g) {
        float s = 0.f;
#pragma unroll
        for (int f = 0; f < 16; ++f) s = fmaf(v[f], con[g][f], s);
        pbuf[(q * 8 + g) * 64 + p] = s;
    }
    __syncthreads();
    for (int k = tid; k < 512; k += 256) {
        const int gg = k >> 6, pp = k & 63;
        const float bs = pbuf[gg * 64 + pp] + pbuf[512 + gg * 64 + pp] +
                         pbuf[1024 + gg * 64 + pp] + pbuf[1536 + gg * 64 + pp];
        betaS[gg * 64 + pp] = bs;
        alphaS[gg * 64 + pp] = 1.f / (1.f + __expf(-bs));
    }
    __syncthreads();

    float a[8];
#pragma unroll
    for (int g = 0; g < 8; ++g) a[g] = alphaS[g * 64 + p];
#pragma unroll
    for (int f = 0; f < 16; ++f) {
        float s = 0.f;
#pragma unroll
        for (int g = 0; g < 8; ++g) s = fmaf(a[g], con[g][f], s);
        v[f] = s;
    }
#pragma unroll
    for (int g = 0; g < 8; ++g) {
        float s = 0.f;
#pragma unroll
        for (int f = 0; f < 16; ++f) s = fmaf(v[f], con[g][f], s);
        pbuf[(q * 8 + g) * 64 + p] = s;
    }
    __syncthreads();
    for (int k = tid; k < 512; k += 256) {
        const int gg = k >> 6, pp = k & 63;
        const float bs = betaS[gg * 64 + pp] +
                         pbuf[gg * 64 + pp] + pbuf[512 + gg * 64 + pp] +
                         pbuf[1024 + gg * 64 + pp] + pbuf[1536 + gg * 64 + pp];
        alphaS[gg * 64 + pp] = 1.f / (1.f + __expf(-bs));
    }
    __syncthreads();

#pragma unroll
    for (int g = 0; g < 8; ++g) a[g] = alphaS[g * 64 + p];

    const float* bq = bias + q * 16;
    float* orow = out + (((size_t)b * NFO + (size_t)q * 16) * NH + h) * NW + p;
#pragma unroll
    for (int f = 0; f < 16; ++f) {
        float s = bq[f];
#pragma unroll
        for (int g = 0; g < 8; ++g) s = fmaf(a[g], con[g][f], s);
        orow[(size_t)f * HW] = s;
    }
}

extern "C" void kernel_launch(void* const* d_in, const int* in_sizes, int n_in,
                              void* d_out, int out_size, void* d_ws, size_t ws_size,
                              hipStream_t stream) {
    const float* x      = (const float*)d_in[0];
    const float* weight = (const float*)d_in[1];
    const float* bias   = (const float*)d_in[2];
    float* out = (float*)d_out;

    const size_t need = (size_t)NB * NG * NFO * HW * sizeof(float);  // 268 MB
    if (d_ws != nullptr && ws_size >= need) {
        float* con = (float*)d_ws;
        conv_kernel<<<dim3(NB * NG * 64), dim3(256), 0, stream>>>(x, weight, con);
        route_kernel<<<dim3(NB * 64), dim3(256), 0, stream>>>(con, bias, out);
    } else {
        dynrout_kernel<<<dim3(NB * NH), dim3(256), 0, stream>>>(x, weight, bias, out);
    }
}